// Round 7
// baseline (516.295 us; speedup 1.0000x reference)
//
#include <hip/hip_runtime.h>
#include <hip/hip_bf16.h>

#define N_NODES 10000
#define N_EDGES 128000
#define C_DIM   128

typedef __attribute__((ext_vector_type(8))) short bf16x8;
typedef __attribute__((ext_vector_type(4))) float f32x4;

// ---------------- helpers ----------------

__device__ __forceinline__ float silu_f(float x) {
  return x / (1.f + __expf(-x));
}

__device__ __forceinline__ unsigned short f2bf(float x) {
  __hip_bfloat16 b = __float2bfloat16(x);
  return *(unsigned short*)&b;
}

__device__ __forceinline__ float bf2f(unsigned short u) {
  __hip_bfloat16 b = *(__hip_bfloat16*)&u;
  return __bfloat162float(b);
}

__device__ __forceinline__ bf16x8 pack8(float4 lo, float4 hi) {
  bf16x8 r;
  r[0] = (short)f2bf(lo.x); r[1] = (short)f2bf(lo.y);
  r[2] = (short)f2bf(lo.z); r[3] = (short)f2bf(lo.w);
  r[4] = (short)f2bf(hi.x); r[5] = (short)f2bf(hi.y);
  r[6] = (short)f2bf(hi.z); r[7] = (short)f2bf(hi.w);
  return r;
}

// ---------------- h = feats @ W_up  [N,128]x[128,128] ----------------
// W column held in VGPRs (128 f32/thread, loaded once, coalesced).
// feats[n][k] is wave-uniform (readfirstlane-hoisted n) -> scalar loads.
#define HB_NODES 40
__global__ __launch_bounds__(256) void k_h(const float* __restrict__ feats,
                                           const float* __restrict__ Wup,
                                           float* __restrict__ h) {
  int tid = threadIdx.x;
  int j = tid & 127;
  int par = tid >> 7;
  int n0 = blockIdx.x * HB_NODES;
  float wreg[128];
  #pragma unroll
  for (int k = 0; k < 128; k++) wreg[k] = Wup[k * 128 + j];
  #pragma unroll 2
  for (int i = par; i < HB_NODES; i += 2) {
    int n = __builtin_amdgcn_readfirstlane(n0 + i);
    const float* fr = &feats[n * 128];
    float acc = 0.f;
    #pragma unroll
    for (int k = 0; k < 128; k++) acc += fr[k] * wreg[k];
    h[n * 128 + j] = acc;
  }
}

// ---------------- weight convert/transpose (bf16), all weights one dispatch --
// wbT[k][v*128+u] = Wskip[(u*10+v)*128+k]   (128 x 1280)
// wlT[l][k][u]    = Wl_l[u*128+k]           (3 x 128 x 128)
// MLP weights into MFMA-B-fragment-linear order:
// index = (ct*KS+ks)*512 + n*32 + (quad*8+j);  value = W[ks*32+t][ct*16+n]
__global__ void k_wcvt(const float* __restrict__ Wskip,
                       const float* __restrict__ Wl0,
                       const float* __restrict__ Wl1,
                       const float* __restrict__ Wl2,
                       const float* __restrict__ W1, const float* __restrict__ W2,
                       const float* __restrict__ W3, const float* __restrict__ W4,
                       unsigned short* __restrict__ wbT,
                       unsigned short* __restrict__ wlT,
                       unsigned short* __restrict__ w1f, unsigned short* __restrict__ w2f,
                       unsigned short* __restrict__ w3f, unsigned short* __restrict__ w4f) {
  int idx = blockIdx.x * 256 + threadIdx.x;
  if (idx < 163840) {
    int j = idx >> 7, k = idx & 127;
    int u = j / 10, v = j - u * 10;
    wbT[k * 1280 + v * 128 + u] = f2bf(Wskip[idx]);
  } else if (idx < 212992) {
    int t = idx - 163840;
    int l = t >> 14, r = t & 16383;
    int u = r >> 7, k = r & 127;
    const float* W = (l == 0) ? Wl0 : (l == 1) ? Wl1 : Wl2;
    wlT[(l * 128 + k) * 128 + u] = f2bf(W[r]);
  } else if (idx < 215040) {               // W1: [8x64] padded K->32, 4 ct
    int j = idx - 212992;
    int ct = j >> 9, r = j & 511, n = r >> 5, t = r & 31;
    w1f[j] = (t < 8) ? f2bf(W1[t * 64 + ct * 16 + n]) : (unsigned short)0;
  } else if (idx < 219136) {               // W2: [64x64], 4 ct x 2 ks
    int j = idx - 215040;
    int ctks = j >> 9, r = j & 511, n = r >> 5, t = r & 31;
    int ct = ctks >> 1, ks = ctks & 1;
    w2f[j] = f2bf(W2[(ks * 32 + t) * 64 + ct * 16 + n]);
  } else if (idx < 223232) {               // W3
    int j = idx - 219136;
    int ctks = j >> 9, r = j & 511, n = r >> 5, t = r & 31;
    int ct = ctks >> 1, ks = ctks & 1;
    w3f[j] = f2bf(W3[(ks * 32 + t) * 64 + ct * 16 + n]);
  } else if (idx < 247808) {               // W4: [64x384], 24 ct x 2 ks
    int j = idx - 223232;
    int ctks = j >> 9, r = j & 511, n = r >> 5, t = r & 31;
    int ct = ctks >> 1, ks = ctks & 1;
    w4f[j] = f2bf(W4[(ks * 32 + t) * 384 + ct * 16 + n]);
  }
}

// ---------------- sc via MFMA: [N x 1280]_z x [1280 x 128] ----------------
__global__ __launch_bounds__(256) void k_sc(const float* __restrict__ f,
                                            const float* __restrict__ at,
                                            const unsigned short* __restrict__ wbT,
                                            float* __restrict__ sc_out) {
  int tid = threadIdx.x;
  int w = tid >> 6, lane = tid & 63;
  int l15 = lane & 15, quad = lane >> 4;
  int n0 = blockIdx.x * 32;

  int nrow[2];
  #pragma unroll
  for (int t = 0; t < 2; t++) {
    int n = n0 + 16 * t + l15;
    nrow[t] = (n < N_NODES) ? n : (N_NODES - 1);
  }
  float4 fA[2][4][2];
  #pragma unroll
  for (int t = 0; t < 2; t++)
    #pragma unroll
    for (int ks = 0; ks < 4; ks++) {
      fA[t][ks][0] = *(const float4*)&f[nrow[t] * 128 + ks * 32 + quad * 8];
      fA[t][ks][1] = *(const float4*)&f[nrow[t] * 128 + ks * 32 + quad * 8 + 4];
    }

  f32x4 acc[2][2] = {};
  #pragma unroll 1
  for (int c = 0; c < 10; c++) {
    float av[2];
    #pragma unroll
    for (int t = 0; t < 2; t++) av[t] = at[nrow[t] * 10 + c];
    bf16x8 af[2][4];
    #pragma unroll
    for (int t = 0; t < 2; t++)
      #pragma unroll
      for (int ks = 0; ks < 4; ks++) {
        float4 lo = fA[t][ks][0], hi = fA[t][ks][1];
        lo.x *= av[t]; lo.y *= av[t]; lo.z *= av[t]; lo.w *= av[t];
        hi.x *= av[t]; hi.y *= av[t]; hi.z *= av[t]; hi.w *= av[t];
        af[t][ks] = pack8(lo, hi);
      }
    #pragma unroll
    for (int kt = 0; kt < 2; kt++) {
      int kcol = w * 32 + kt * 16 + l15;
      #pragma unroll
      for (int ks = 0; ks < 4; ks++) {
        bf16x8 bf = *(const bf16x8*)&wbT[kcol * 1280 + c * 128 + ks * 32 + quad * 8];
        #pragma unroll
        for (int t = 0; t < 2; t++)
          acc[t][kt] = __builtin_amdgcn_mfma_f32_16x16x32_bf16(af[t][ks], bf,
                                                               acc[t][kt], 0, 0, 0);
      }
    }
  }
  #pragma unroll
  for (int t = 0; t < 2; t++)
    #pragma unroll
    for (int kt = 0; kt < 2; kt++) {
      int kcol = w * 32 + kt * 16 + l15;
      #pragma unroll
      for (int reg = 0; reg < 4; reg++) {
        int n = n0 + 16 * t + quad * 4 + reg;
        if (n < N_NODES)
          __builtin_nontemporal_store(acc[t][kt][reg], &sc_out[n * 128 + kcol]);
      }
    }
}

// ---------------- fused edge MLP via MFMA (bf16) ----------------
// 128 edges/block, 4 waves; wave w owns edge rows [w*32, w*32+32).
// Barrier-free: every LDS access stays in the wave's own 32-row stripe.
__global__ __launch_bounds__(256) void k_mlp(const float* __restrict__ ef,
                                             const int* __restrict__ order,
                                             const unsigned short* __restrict__ w1f,
                                             const unsigned short* __restrict__ w2f,
                                             const unsigned short* __restrict__ w3f,
                                             const unsigned short* __restrict__ w4f,
                                             unsigned short* __restrict__ tpw) {
  __shared__ unsigned short sA[128][72];
  __shared__ unsigned short sB[128][72];
  int tid = threadIdx.x;
  int w = tid >> 6, lane = tid & 63;
  int l15 = lane & 15, quad = lane >> 4;
  int e0 = blockIdx.x * 128;
  int fragoff = l15 * 32 + quad * 8;
  int rb = w * 32;

  // ---- L1: 8 -> 64 (K padded to 32; only quad 0 carries data) ----
  {
    bf16x8 af[2];
    #pragma unroll
    for (int rt = 0; rt < 2; rt++) {
      bf16x8 a = {};
      if (quad == 0) {
        int pos = e0 + rb + rt * 16 + l15;
        int e = order[pos];
        float4 lo = *(const float4*)&ef[e * 8];
        float4 hi = *(const float4*)&ef[e * 8 + 4];
        a = pack8(lo, hi);
      }
      af[rt] = a;
    }
    f32x4 ac[2][4] = {};
    #pragma unroll
    for (int ct = 0; ct < 4; ct++) {
      bf16x8 b = *(const bf16x8*)&w1f[ct * 512 + fragoff];
      ac[0][ct] = __builtin_amdgcn_mfma_f32_16x16x32_bf16(af[0], b, ac[0][ct], 0, 0, 0);
      ac[1][ct] = __builtin_amdgcn_mfma_f32_16x16x32_bf16(af[1], b, ac[1][ct], 0, 0, 0);
    }
    #pragma unroll
    for (int rt = 0; rt < 2; rt++)
      #pragma unroll
      for (int ct = 0; ct < 4; ct++)
        #pragma unroll
        for (int reg = 0; reg < 4; reg++)
          sA[rb + rt * 16 + quad * 4 + reg][ct * 16 + l15] =
              f2bf(silu_f(ac[rt][ct][reg]));
  }
  asm volatile("" ::: "memory");

  // ---- L2: sA -> sB ; L3: sB -> sA (own stripe only) ----
  #pragma unroll 1
  for (int layer = 0; layer < 2; layer++) {
    unsigned short (*src)[72] = (layer == 0) ? sA : sB;
    unsigned short (*dst)[72] = (layer == 0) ? sB : sA;
    const unsigned short* wf = (layer == 0) ? w2f : w3f;
    bf16x8 a2[2][2];
    #pragma unroll
    for (int rt = 0; rt < 2; rt++)
      #pragma unroll
      for (int ks = 0; ks < 2; ks++)
        a2[rt][ks] = *(const bf16x8*)&src[rb + rt * 16 + l15][ks * 32 + quad * 8];
    f32x4 ac[2][4] = {};
    #pragma unroll
    for (int ct = 0; ct < 4; ct++)
      #pragma unroll
      for (int ks = 0; ks < 2; ks++) {
        bf16x8 b = *(const bf16x8*)&wf[(ct * 2 + ks) * 512 + fragoff];
        ac[0][ct] = __builtin_amdgcn_mfma_f32_16x16x32_bf16(a2[0][ks], b, ac[0][ct], 0, 0, 0);
        ac[1][ct] = __builtin_amdgcn_mfma_f32_16x16x32_bf16(a2[1][ks], b, ac[1][ct], 0, 0, 0);
      }
    #pragma unroll
    for (int rt = 0; rt < 2; rt++)
      #pragma unroll
      for (int ct = 0; ct < 4; ct++)
        #pragma unroll
        for (int reg = 0; reg < 4; reg++)
          dst[rb + rt * 16 + quad * 4 + reg][ct * 16 + l15] =
              f2bf(silu_f(ac[rt][ct][reg]));
    asm volatile("" ::: "memory");
  }

  // ---- L4: 64 -> 384, 6 chunks of 64 cols; C -> sB -> per-wave store ----
  bf16x8 a4[2][2];
  #pragma unroll
  for (int rt = 0; rt < 2; rt++)
    #pragma unroll
    for (int ks = 0; ks < 2; ks++)
      a4[rt][ks] = *(const bf16x8*)&sA[rb + rt * 16 + l15][ks * 32 + quad * 8];

  #pragma unroll 1
  for (int ch = 0; ch < 6; ch++) {
    f32x4 ac[2][4] = {};
    #pragma unroll
    for (int ct = 0; ct < 4; ct++)
      #pragma unroll
      for (int ks = 0; ks < 2; ks++) {
        bf16x8 b = *(const bf16x8*)&w4f[((ch * 4 + ct) * 2 + ks) * 512 + fragoff];
        ac[0][ct] = __builtin_amdgcn_mfma_f32_16x16x32_bf16(a4[0][ks], b, ac[0][ct], 0, 0, 0);
        ac[1][ct] = __builtin_amdgcn_mfma_f32_16x16x32_bf16(a4[1][ks], b, ac[1][ct], 0, 0, 0);
      }
    #pragma unroll
    for (int rt = 0; rt < 2; rt++)
      #pragma unroll
      for (int ct = 0; ct < 4; ct++)
        #pragma unroll
        for (int reg = 0; reg < 4; reg++)
          sB[rb + rt * 16 + quad * 4 + reg][ct * 16 + l15] = f2bf(ac[rt][ct][reg]);
    asm volatile("" ::: "memory");
    // per-wave store-out: wave w stores rows rb..rb+31 of this chunk
    #pragma unroll
    for (int v = 0; v < 4; v++) {
      int idx = v * 64 + lane;
      int r = idx >> 3, cg = idx & 7;
      uint4 p = *(const uint4*)&sB[rb + r][cg * 8];
      *(uint4*)&tpw[(size_t)(e0 + rb + r) * 384 + ch * 64 + cg * 8] = p;
    }
    asm volatile("" ::: "memory");
  }
}

// ---------------- CSR build ----------------
__global__ void k_hist(const int* __restrict__ recv, int* __restrict__ counts) {
  int e = blockIdx.x * 256 + threadIdx.x;
  if (e < N_EDGES) atomicAdd(&counts[recv[e]], 1);
}

// shuffle-based scan: 2 barriers instead of 20.
__global__ __launch_bounds__(1024) void k_scan(const int* __restrict__ counts,
                                               int* __restrict__ offsets,
                                               int* __restrict__ cursor) {
  __shared__ int swave[16];
  int tid = threadIdx.x;
  int lane = tid & 63, w = tid >> 6;
  int base = tid * 10;
  int local[10]; int s = 0;
  #pragma unroll
  for (int i = 0; i < 10; i++) {
    int idx = base + i;
    int c = (idx < N_NODES) ? counts[idx] : 0;
    local[i] = s; s += c;
  }
  // inclusive wave scan of s
  int inc = s;
  #pragma unroll
  for (int d = 1; d < 64; d <<= 1) {
    int v = __shfl_up(inc, d, 64);
    if (lane >= d) inc += v;
  }
  if (lane == 63) swave[w] = inc;
  __syncthreads();
  if (w == 0) {
    int t = (lane < 16) ? swave[lane] : 0;
    #pragma unroll
    for (int d = 1; d < 16; d <<= 1) {
      int v = __shfl_up(t, d, 64);
      if (lane >= d) t += v;
    }
    if (lane < 16) swave[lane] = t;   // inclusive wave-prefix
  }
  __syncthreads();
  int wpre = (w > 0) ? swave[w - 1] : 0;
  int pre = wpre + (inc - s);         // exclusive prefix for this thread
  #pragma unroll
  for (int i = 0; i < 10; i++) {
    int idx = base + i;
    if (idx < N_NODES) { int o = pre + local[i]; offsets[idx] = o; cursor[idx] = o; }
  }
  if (tid == 1023) offsets[N_NODES] = wpre + inc;
}

// scatter builds order AND the CSR-sorted y2/ss streams directly.
__global__ void k_scatter(const int* __restrict__ recv, const int* __restrict__ send,
                          const float* __restrict__ yr, const float* __restrict__ yi,
                          int* __restrict__ cursor, int* __restrict__ order,
                          float* __restrict__ y2, int* __restrict__ ss) {
  int e = blockIdx.x * 256 + threadIdx.x;
  if (e < N_EDGES) {
    int idx = atomicAdd(&cursor[recv[e]], 1);
    order[idx] = e;
    ss[idx] = send[e];
    float* yy = &y2[(size_t)idx * 20];
    #pragma unroll
    for (int m = 0; m < 9; m++) {
      yy[m] = yr[e * 9 + m];
      yy[9 + m] = yi[e * 9 + m];
    }
    yy[18] = 0.f; yy[19] = 0.f;
  }
}

// ---------------- fused gather + linear ----------------
// One block per group g of 8 nodes. Phase 1: two 128-thread teams gather
// 4 nodes each (conv_tp + segment-sum, 4-edge load batching, NT tpw reads),
// writing the 144x128 msg tile into LDS (rows padded to 136 bf16 so the
// phase-2 ds_read_b128 at row-stride lands on shifting banks, <=2-way).
// Phase 2: k_lin's MFMA body reads fragments from LDS; output staged in
// a row-padded LDS f32 tile then written out as coalesced NT float4s.
// Removes the 46 MB msg HBM round-trip entirely.
#define SMSG_PAD 136
#define LIN_ROWPAD 1156   // 1152 + 4 floats; 1156*4 B is 16B-aligned

__device__ __forceinline__ void edge_fma(const float* __restrict__ y2, int pos,
                                         float xv, float t0, float t1, float t2,
                                         float* mr, float* mi) {
  const float* yy = &y2[(size_t)pos * 20];
  float4 v0 = *(const float4*)&yy[0];    // r0 r1 r2 r3
  float4 v1 = *(const float4*)&yy[4];    // r4 r5 r6 r7
  float4 v2 = *(const float4*)&yy[8];    // r8 i0 i1 i2
  float4 v3 = *(const float4*)&yy[12];   // i3 i4 i5 i6
  float2 v4 = *(const float2*)&yy[16];   // i7 i8
  float xw0 = xv * t0, xw1 = xv * t1, xw2 = xv * t2;
  mr[0] += xw0 * v0.x;
  mr[1] += xw1 * v0.y; mr[2] += xw1 * v0.z; mr[3] += xw1 * v0.w;
  mr[4] += xw2 * v1.x; mr[5] += xw2 * v1.y; mr[6] += xw2 * v1.z;
  mr[7] += xw2 * v1.w; mr[8] += xw2 * v2.x;
  mi[0] += xw0 * v2.y;
  mi[1] += xw1 * v2.z; mi[2] += xw1 * v2.w; mi[3] += xw1 * v3.x;
  mi[4] += xw2 * v3.y; mi[5] += xw2 * v3.z; mi[6] += xw2 * v3.w;
  mi[7] += xw2 * v4.x; mi[8] += xw2 * v4.y;
}

__global__ __launch_bounds__(256, 1) void k_gl(
    const float* __restrict__ h, const unsigned short* __restrict__ tpw,
    const float* __restrict__ y2, const int* __restrict__ ss,
    const int* __restrict__ offsets,
    const unsigned short* __restrict__ wlT,
    float* __restrict__ out) {
  __shared__ unsigned short smsg[144 * SMSG_PAD];   // 39,168 B
  __shared__ float so[2 * 8 * LIN_ROWPAD];          // 73,984 B
  int tid = threadIdx.x;
  int g = blockIdx.x;

  // ================= phase 1: gather 8 nodes into smsg =================
  {
    int u = tid & 127;
    int team = tid >> 7;                 // 0 or 1
    #pragma unroll 1
    for (int t = 0; t < 4; t++) {
      int i = team * 4 + t;              // node-in-group 0..7
      int n = g * 8 + i;
      float mr[9] = {}, mi[9] = {};
      int e0 = __builtin_amdgcn_readfirstlane(offsets[n]);
      int e1 = __builtin_amdgcn_readfirstlane(offsets[n + 1]);
      int jj = e0;
      for (; jj + 3 < e1; jj += 4) {
        float xv[4], t0[4], t1[4], t2[4];
        #pragma unroll
        for (int q = 0; q < 4; q++) {
          int pos = jj + q;
          int s = ss[pos];
          const unsigned short* tp = &tpw[(size_t)pos * 384 + u];
          t0[q] = bf2f(__builtin_nontemporal_load(tp));
          t1[q] = bf2f(__builtin_nontemporal_load(tp + 128));
          t2[q] = bf2f(__builtin_nontemporal_load(tp + 256));
          xv[q] = h[s * 128 + u];
        }
        #pragma unroll
        for (int q = 0; q < 4; q++)
          edge_fma(y2, jj + q, xv[q], t0[q], t1[q], t2[q], mr, mi);
      }
      for (; jj < e1; jj++) {
        int s = ss[jj];
        const unsigned short* tp = &tpw[(size_t)jj * 384 + u];
        float t0 = bf2f(__builtin_nontemporal_load(tp));
        float t1 = bf2f(__builtin_nontemporal_load(tp + 128));
        float t2 = bf2f(__builtin_nontemporal_load(tp + 256));
        float xv = h[s * 128 + u];
        edge_fma(y2, jj, xv, t0, t1, t2, mr, mi);
      }
      smsg[(i * 2 + 0) * SMSG_PAD + u] = f2bf(mr[0]);
      smsg[(i * 2 + 1) * SMSG_PAD + u] = f2bf(mi[0]);
      #pragma unroll
      for (int m = 1; m < 4; m++) {
        smsg[(16 + i * 6 + (m - 1)) * SMSG_PAD + u] = f2bf(mr[m]);
        smsg[(16 + i * 6 + 3 + (m - 1)) * SMSG_PAD + u] = f2bf(mi[m]);
      }
      #pragma unroll
      for (int m = 4; m < 9; m++) {
        smsg[(64 + i * 10 + (m - 4)) * SMSG_PAD + u] = f2bf(mr[m]);
        smsg[(64 + i * 10 + 5 + (m - 4)) * SMSG_PAD + u] = f2bf(mi[m]);
      }
    }
  }
  __syncthreads();

  // ================= phase 2: linear (k_lin body, msg from LDS) =========
  {
    int w = tid >> 6, lane = tid & 63;
    int l15 = lane & 15, quad = lane >> 4;

    bf16x8 bfr[3][2][4];
    #pragma unroll
    for (int l = 0; l < 3; l++)
      #pragma unroll
      for (int kt = 0; kt < 2; kt++)
        #pragma unroll
        for (int ks = 0; ks < 4; ks++) {
          int ncol = w * 32 + kt * 16 + l15;
          bfr[l][kt][ks] =
              *(const bf16x8*)&wlT[(l * 128 + ncol) * 128 + ks * 32 + quad * 8];
        }

    #pragma unroll
    for (int tile = 0; tile < 9; tile++) {
      const int l = (tile == 0) ? 0 : (tile < 4) ? 1 : 2;
      const int rbase = tile * 16;
      bf16x8 af[4];
      #pragma unroll
      for (int ks = 0; ks < 4; ks++)
        af[ks] = *(const bf16x8*)&smsg[(rbase + l15) * SMSG_PAD + ks * 32 + quad * 8];
      f32x4 acc0 = {}, acc1 = {};
      #pragma unroll
      for (int ks = 0; ks < 4; ks++) {
        acc0 = __builtin_amdgcn_mfma_f32_16x16x32_bf16(af[ks], bfr[l][0][ks], acc0, 0, 0, 0);
        acc1 = __builtin_amdgcn_mfma_f32_16x16x32_bf16(af[ks], bfr[l][1][ks], acc1, 0, 0, 0);
      }
      #pragma unroll
      for (int reg = 0; reg < 4; reg++) {
        int r = rbase + quad * 4 + reg;
        int c, ni, m;
        if (tile == 0) { ni = (r & 15) >> 1; c = r & 1; m = 0; }
        else if (tile < 4) {
          int q = r - 16; ni = q / 6; int rem = q - ni * 6;
          c = rem >= 3; m = 1 + rem - (c ? 3 : 0);
        } else {
          int q = r - 64; ni = q / 10; int rem = q - ni * 10;
          c = rem >= 5; m = 4 + rem - (c ? 5 : 0);
        }
        int k0 = w * 32 + l15;
        float* ob = &so[(c * 8 + ni) * LIN_ROWPAD + m];
        ob[(k0)      * 9] = acc0[reg];
        ob[(k0 + 16) * 9] = acc1[reg];
      }
    }
    __syncthreads();
    // cooperative coalesced write-out: 2*8*1152 floats = 4608 float4
    #pragma unroll
    for (int v = 0; v < 18; v++) {
      int idx = v * 256 + tid;
      int c = idx / 2304;
      int rem = idx - c * 2304;
      int ni = rem / 288;
      int off4 = rem - ni * 288;
      f32x4 p = *(const f32x4*)&so[(c * 8 + ni) * LIN_ROWPAD + off4 * 4];
      f32x4* dst = (f32x4*)&out[(size_t)c * 11520000 + ((size_t)g * 8 + ni) * 1152 +
                                (size_t)off4 * 4];
      __builtin_nontemporal_store(p, dst);
    }
  }
}

// ---------------- launch ----------------
extern "C" void kernel_launch(void* const* d_in, const int* in_sizes, int n_in,
                              void* d_out, int out_size, void* d_ws, size_t ws_size,
                              hipStream_t stream) {
  const float* node_attrs = (const float*)d_in[0];
  const float* node_feats = (const float*)d_in[1];
  const float* ear   = (const float*)d_in[2];
  const float* eai   = (const float*)d_in[3];
  const float* ef    = (const float*)d_in[4];
  const int*   eidx  = (const int*)d_in[5];
  const float* Wup   = (const float*)d_in[6];
  const float* Wskip = (const float*)d_in[7];
  const float* W1    = (const float*)d_in[8];
  const float* W2    = (const float*)d_in[9];
  const float* W3    = (const float*)d_in[10];
  const float* W4    = (const float*)d_in[11];
  const float* Wl0   = (const float*)d_in[12];
  const float* Wl1   = (const float*)d_in[13];
  const float* Wl2   = (const float*)d_in[14];
  float* out = (float*)d_out;

  // workspace layout (bytes):
  char* ws = (char*)d_ws;
  float*          h       = (float*)ws;                              //   5,120,000
  unsigned short* tpw     = (unsigned short*)(ws + 5120000);         //  98,304,000
  // former msg region (freed by the gather+lin fusion) now hosts y2/ss:
  float*          y2      = (float*)(ws + 103424000);                //  10,240,000
  int*            ss      = (int*)(ws + 113664000);                  //     512,000
  unsigned short* wlT     = (unsigned short*)(ws + 149504000);       //      98,304
  unsigned short* wbT     = (unsigned short*)(ws + 149602304);       //     327,680
  int*            counts  = (int*)(ws + 149929984);
  int*            offsets = (int*)(ws + 149969984);
  int*            cursor  = (int*)(ws + 150010112);
  int*            order   = (int*)(ws + 150050112);                  //     512,000
  unsigned short* w1f     = (unsigned short*)(ws + 150562816);       //       4,096
  unsigned short* w2f     = (unsigned short*)(ws + 150566912);       //       8,192
  unsigned short* w3f     = (unsigned short*)(ws + 150575104);       //       8,192
  unsigned short* w4f     = (unsigned short*)(ws + 150583296);       //      49,152

  const int* send = eidx;
  const int* recv = eidx + N_EDGES;

  hipMemsetAsync(counts, 0, N_NODES * sizeof(int), stream);
  k_hist<<<dim3(500), dim3(256), 0, stream>>>(recv, counts);
  k_scan<<<dim3(1), dim3(1024), 0, stream>>>(counts, offsets, cursor);
  k_scatter<<<dim3(500), dim3(256), 0, stream>>>(recv, send, ear, eai, cursor,
                                                 order, y2, ss);
  k_wcvt<<<dim3(968), dim3(256), 0, stream>>>(Wskip, Wl0, Wl1, Wl2,
                                              W1, W2, W3, W4,
                                              wbT, wlT, w1f, w2f, w3f, w4f);
  k_h<<<dim3(250), dim3(256), 0, stream>>>(node_feats, Wup, h);
  k_sc<<<dim3(313), dim3(256), 0, stream>>>(node_feats, node_attrs, wbT,
                                            out + 2 * 11520000);
  k_mlp<<<dim3(1000), dim3(256), 0, stream>>>(ef, order, w1f, w2f, w3f, w4f, tpw);
  k_gl<<<dim3(1250), dim3(256), 0, stream>>>(h, tpw, y2, ss, offsets, wlT, out);
  (void)in_sizes; (void)n_in; (void)out_size; (void)ws_size;
}

// Round 8
// 332.957 us; speedup vs baseline: 1.5506x; 1.5506x over previous
//
#include <hip/hip_runtime.h>
#include <hip/hip_bf16.h>

#define N_NODES 10000
#define N_EDGES 128000
#define C_DIM   128

typedef __attribute__((ext_vector_type(8))) short bf16x8;
typedef __attribute__((ext_vector_type(4))) float f32x4;

// ---------------- helpers ----------------

__device__ __forceinline__ float silu_f(float x) {
  return x / (1.f + __expf(-x));
}

__device__ __forceinline__ unsigned short f2bf(float x) {
  __hip_bfloat16 b = __float2bfloat16(x);
  return *(unsigned short*)&b;
}

__device__ __forceinline__ float bf2f(unsigned short u) {
  __hip_bfloat16 b = *(__hip_bfloat16*)&u;
  return __bfloat162float(b);
}

__device__ __forceinline__ bf16x8 pack8(float4 lo, float4 hi) {
  bf16x8 r;
  r[0] = (short)f2bf(lo.x); r[1] = (short)f2bf(lo.y);
  r[2] = (short)f2bf(lo.z); r[3] = (short)f2bf(lo.w);
  r[4] = (short)f2bf(hi.x); r[5] = (short)f2bf(hi.y);
  r[6] = (short)f2bf(hi.z); r[7] = (short)f2bf(hi.w);
  return r;
}

// ---------------- h = feats @ W_up  [N,128]x[128,128] ----------------
// W column held in VGPRs (128 f32/thread, loaded once, coalesced).
// feats[n][k] is wave-uniform (readfirstlane-hoisted n) -> scalar loads.
#define HB_NODES 40
__global__ __launch_bounds__(256) void k_h(const float* __restrict__ feats,
                                           const float* __restrict__ Wup,
                                           float* __restrict__ h) {
  int tid = threadIdx.x;
  int j = tid & 127;
  int par = tid >> 7;
  int n0 = blockIdx.x * HB_NODES;
  float wreg[128];
  #pragma unroll
  for (int k = 0; k < 128; k++) wreg[k] = Wup[k * 128 + j];
  #pragma unroll 2
  for (int i = par; i < HB_NODES; i += 2) {
    int n = __builtin_amdgcn_readfirstlane(n0 + i);
    const float* fr = &feats[n * 128];
    float acc = 0.f;
    #pragma unroll
    for (int k = 0; k < 128; k++) acc += fr[k] * wreg[k];
    h[n * 128 + j] = acc;
  }
}

// ---------------- weight convert/transpose (bf16), all weights one dispatch --
// wbT[k][v*128+u] = Wskip[(u*10+v)*128+k]   (128 x 1280)
// wlT[l][k][u]    = Wl_l[u*128+k]           (3 x 128 x 128)
// MLP weights into MFMA-B-fragment-linear order:
// index = (ct*KS+ks)*512 + n*32 + (quad*8+j);  value = W[ks*32+t][ct*16+n]
__global__ void k_wcvt(const float* __restrict__ Wskip,
                       const float* __restrict__ Wl0,
                       const float* __restrict__ Wl1,
                       const float* __restrict__ Wl2,
                       const float* __restrict__ W1, const float* __restrict__ W2,
                       const float* __restrict__ W3, const float* __restrict__ W4,
                       unsigned short* __restrict__ wbT,
                       unsigned short* __restrict__ wlT,
                       unsigned short* __restrict__ w1f, unsigned short* __restrict__ w2f,
                       unsigned short* __restrict__ w3f, unsigned short* __restrict__ w4f) {
  int idx = blockIdx.x * 256 + threadIdx.x;
  if (idx < 163840) {
    int j = idx >> 7, k = idx & 127;
    int u = j / 10, v = j - u * 10;
    wbT[k * 1280 + v * 128 + u] = f2bf(Wskip[idx]);
  } else if (idx < 212992) {
    int t = idx - 163840;
    int l = t >> 14, r = t & 16383;
    int u = r >> 7, k = r & 127;
    const float* W = (l == 0) ? Wl0 : (l == 1) ? Wl1 : Wl2;
    wlT[(l * 128 + k) * 128 + u] = f2bf(W[r]);
  } else if (idx < 215040) {               // W1: [8x64] padded K->32, 4 ct
    int j = idx - 212992;
    int ct = j >> 9, r = j & 511, n = r >> 5, t = r & 31;
    w1f[j] = (t < 8) ? f2bf(W1[t * 64 + ct * 16 + n]) : (unsigned short)0;
  } else if (idx < 219136) {               // W2: [64x64], 4 ct x 2 ks
    int j = idx - 215040;
    int ctks = j >> 9, r = j & 511, n = r >> 5, t = r & 31;
    int ct = ctks >> 1, ks = ctks & 1;
    w2f[j] = f2bf(W2[(ks * 32 + t) * 64 + ct * 16 + n]);
  } else if (idx < 223232) {               // W3
    int j = idx - 219136;
    int ctks = j >> 9, r = j & 511, n = r >> 5, t = r & 31;
    int ct = ctks >> 1, ks = ctks & 1;
    w3f[j] = f2bf(W3[(ks * 32 + t) * 64 + ct * 16 + n]);
  } else if (idx < 247808) {               // W4: [64x384], 24 ct x 2 ks
    int j = idx - 223232;
    int ctks = j >> 9, r = j & 511, n = r >> 5, t = r & 31;
    int ct = ctks >> 1, ks = ctks & 1;
    w4f[j] = f2bf(W4[(ks * 32 + t) * 384 + ct * 16 + n]);
  }
}

// ---------------- sc via MFMA: [N x 1280]_z x [1280 x 128] ----------------
__global__ __launch_bounds__(256) void k_sc(const float* __restrict__ f,
                                            const float* __restrict__ at,
                                            const unsigned short* __restrict__ wbT,
                                            float* __restrict__ sc_out) {
  int tid = threadIdx.x;
  int w = tid >> 6, lane = tid & 63;
  int l15 = lane & 15, quad = lane >> 4;
  int n0 = blockIdx.x * 32;

  int nrow[2];
  #pragma unroll
  for (int t = 0; t < 2; t++) {
    int n = n0 + 16 * t + l15;
    nrow[t] = (n < N_NODES) ? n : (N_NODES - 1);
  }
  float4 fA[2][4][2];
  #pragma unroll
  for (int t = 0; t < 2; t++)
    #pragma unroll
    for (int ks = 0; ks < 4; ks++) {
      fA[t][ks][0] = *(const float4*)&f[nrow[t] * 128 + ks * 32 + quad * 8];
      fA[t][ks][1] = *(const float4*)&f[nrow[t] * 128 + ks * 32 + quad * 8 + 4];
    }

  f32x4 acc[2][2] = {};
  #pragma unroll 1
  for (int c = 0; c < 10; c++) {
    float av[2];
    #pragma unroll
    for (int t = 0; t < 2; t++) av[t] = at[nrow[t] * 10 + c];
    bf16x8 af[2][4];
    #pragma unroll
    for (int t = 0; t < 2; t++)
      #pragma unroll
      for (int ks = 0; ks < 4; ks++) {
        float4 lo = fA[t][ks][0], hi = fA[t][ks][1];
        lo.x *= av[t]; lo.y *= av[t]; lo.z *= av[t]; lo.w *= av[t];
        hi.x *= av[t]; hi.y *= av[t]; hi.z *= av[t]; hi.w *= av[t];
        af[t][ks] = pack8(lo, hi);
      }
    #pragma unroll
    for (int kt = 0; kt < 2; kt++) {
      int kcol = w * 32 + kt * 16 + l15;
      #pragma unroll
      for (int ks = 0; ks < 4; ks++) {
        bf16x8 bf = *(const bf16x8*)&wbT[kcol * 1280 + c * 128 + ks * 32 + quad * 8];
        #pragma unroll
        for (int t = 0; t < 2; t++)
          acc[t][kt] = __builtin_amdgcn_mfma_f32_16x16x32_bf16(af[t][ks], bf,
                                                               acc[t][kt], 0, 0, 0);
      }
    }
  }
  #pragma unroll
  for (int t = 0; t < 2; t++)
    #pragma unroll
    for (int kt = 0; kt < 2; kt++) {
      int kcol = w * 32 + kt * 16 + l15;
      #pragma unroll
      for (int reg = 0; reg < 4; reg++) {
        int n = n0 + 16 * t + quad * 4 + reg;
        if (n < N_NODES)
          __builtin_nontemporal_store(acc[t][kt][reg], &sc_out[n * 128 + kcol]);
      }
    }
}

// ---------------- fused edge MLP via MFMA (bf16) ----------------
// 128 edges/block, 4 waves; wave w owns edge rows [w*32, w*32+32).
// Barrier-free: every LDS access stays in the wave's own 32-row stripe.
__global__ __launch_bounds__(256) void k_mlp(const float* __restrict__ ef,
                                             const int* __restrict__ order,
                                             const unsigned short* __restrict__ w1f,
                                             const unsigned short* __restrict__ w2f,
                                             const unsigned short* __restrict__ w3f,
                                             const unsigned short* __restrict__ w4f,
                                             unsigned short* __restrict__ tpw) {
  __shared__ unsigned short sA[128][72];
  __shared__ unsigned short sB[128][72];
  int tid = threadIdx.x;
  int w = tid >> 6, lane = tid & 63;
  int l15 = lane & 15, quad = lane >> 4;
  int e0 = blockIdx.x * 128;
  int fragoff = l15 * 32 + quad * 8;
  int rb = w * 32;

  // ---- L1: 8 -> 64 (K padded to 32; only quad 0 carries data) ----
  {
    bf16x8 af[2];
    #pragma unroll
    for (int rt = 0; rt < 2; rt++) {
      bf16x8 a = {};
      if (quad == 0) {
        int pos = e0 + rb + rt * 16 + l15;
        int e = order[pos];
        float4 lo = *(const float4*)&ef[e * 8];
        float4 hi = *(const float4*)&ef[e * 8 + 4];
        a = pack8(lo, hi);
      }
      af[rt] = a;
    }
    f32x4 ac[2][4] = {};
    #pragma unroll
    for (int ct = 0; ct < 4; ct++) {
      bf16x8 b = *(const bf16x8*)&w1f[ct * 512 + fragoff];
      ac[0][ct] = __builtin_amdgcn_mfma_f32_16x16x32_bf16(af[0], b, ac[0][ct], 0, 0, 0);
      ac[1][ct] = __builtin_amdgcn_mfma_f32_16x16x32_bf16(af[1], b, ac[1][ct], 0, 0, 0);
    }
    #pragma unroll
    for (int rt = 0; rt < 2; rt++)
      #pragma unroll
      for (int ct = 0; ct < 4; ct++)
        #pragma unroll
        for (int reg = 0; reg < 4; reg++)
          sA[rb + rt * 16 + quad * 4 + reg][ct * 16 + l15] =
              f2bf(silu_f(ac[rt][ct][reg]));
  }
  asm volatile("" ::: "memory");

  // ---- L2: sA -> sB ; L3: sB -> sA (own stripe only) ----
  #pragma unroll 1
  for (int layer = 0; layer < 2; layer++) {
    unsigned short (*src)[72] = (layer == 0) ? sA : sB;
    unsigned short (*dst)[72] = (layer == 0) ? sB : sA;
    const unsigned short* wf = (layer == 0) ? w2f : w3f;
    bf16x8 a2[2][2];
    #pragma unroll
    for (int rt = 0; rt < 2; rt++)
      #pragma unroll
      for (int ks = 0; ks < 2; ks++)
        a2[rt][ks] = *(const bf16x8*)&src[rb + rt * 16 + l15][ks * 32 + quad * 8];
    f32x4 ac[2][4] = {};
    #pragma unroll
    for (int ct = 0; ct < 4; ct++)
      #pragma unroll
      for (int ks = 0; ks < 2; ks++) {
        bf16x8 b = *(const bf16x8*)&wf[(ct * 2 + ks) * 512 + fragoff];
        ac[0][ct] = __builtin_amdgcn_mfma_f32_16x16x32_bf16(a2[0][ks], b, ac[0][ct], 0, 0, 0);
        ac[1][ct] = __builtin_amdgcn_mfma_f32_16x16x32_bf16(a2[1][ks], b, ac[1][ct], 0, 0, 0);
      }
    #pragma unroll
    for (int rt = 0; rt < 2; rt++)
      #pragma unroll
      for (int ct = 0; ct < 4; ct++)
        #pragma unroll
        for (int reg = 0; reg < 4; reg++)
          dst[rb + rt * 16 + quad * 4 + reg][ct * 16 + l15] =
              f2bf(silu_f(ac[rt][ct][reg]));
    asm volatile("" ::: "memory");
  }

  // ---- L4: 64 -> 384, 6 chunks of 64 cols; C -> sB -> per-wave store ----
  bf16x8 a4[2][2];
  #pragma unroll
  for (int rt = 0; rt < 2; rt++)
    #pragma unroll
    for (int ks = 0; ks < 2; ks++)
      a4[rt][ks] = *(const bf16x8*)&sA[rb + rt * 16 + l15][ks * 32 + quad * 8];

  #pragma unroll 1
  for (int ch = 0; ch < 6; ch++) {
    f32x4 ac[2][4] = {};
    #pragma unroll
    for (int ct = 0; ct < 4; ct++)
      #pragma unroll
      for (int ks = 0; ks < 2; ks++) {
        bf16x8 b = *(const bf16x8*)&w4f[((ch * 4 + ct) * 2 + ks) * 512 + fragoff];
        ac[0][ct] = __builtin_amdgcn_mfma_f32_16x16x32_bf16(a4[0][ks], b, ac[0][ct], 0, 0, 0);
        ac[1][ct] = __builtin_amdgcn_mfma_f32_16x16x32_bf16(a4[1][ks], b, ac[1][ct], 0, 0, 0);
      }
    #pragma unroll
    for (int rt = 0; rt < 2; rt++)
      #pragma unroll
      for (int ct = 0; ct < 4; ct++)
        #pragma unroll
        for (int reg = 0; reg < 4; reg++)
          sB[rb + rt * 16 + quad * 4 + reg][ct * 16 + l15] = f2bf(ac[rt][ct][reg]);
    asm volatile("" ::: "memory");
    // per-wave store-out: wave w stores rows rb..rb+31 of this chunk
    #pragma unroll
    for (int v = 0; v < 4; v++) {
      int idx = v * 64 + lane;
      int r = idx >> 3, cg = idx & 7;
      uint4 p = *(const uint4*)&sB[rb + r][cg * 8];
      *(uint4*)&tpw[(size_t)(e0 + rb + r) * 384 + ch * 64 + cg * 8] = p;
    }
    asm volatile("" ::: "memory");
  }
}

// ---------------- CSR build ----------------
__global__ void k_hist(const int* __restrict__ recv, int* __restrict__ counts) {
  int e = blockIdx.x * 256 + threadIdx.x;
  if (e < N_EDGES) atomicAdd(&counts[recv[e]], 1);
}

// shuffle-based scan: 2 barriers instead of 20.
__global__ __launch_bounds__(1024) void k_scan(const int* __restrict__ counts,
                                               int* __restrict__ offsets,
                                               int* __restrict__ cursor) {
  __shared__ int swave[16];
  int tid = threadIdx.x;
  int lane = tid & 63, w = tid >> 6;
  int base = tid * 10;
  int local[10]; int s = 0;
  #pragma unroll
  for (int i = 0; i < 10; i++) {
    int idx = base + i;
    int c = (idx < N_NODES) ? counts[idx] : 0;
    local[i] = s; s += c;
  }
  // inclusive wave scan of s
  int inc = s;
  #pragma unroll
  for (int d = 1; d < 64; d <<= 1) {
    int v = __shfl_up(inc, d, 64);
    if (lane >= d) inc += v;
  }
  if (lane == 63) swave[w] = inc;
  __syncthreads();
  if (w == 0) {
    int t = (lane < 16) ? swave[lane] : 0;
    #pragma unroll
    for (int d = 1; d < 16; d <<= 1) {
      int v = __shfl_up(t, d, 64);
      if (lane >= d) t += v;
    }
    if (lane < 16) swave[lane] = t;   // inclusive wave-prefix
  }
  __syncthreads();
  int wpre = (w > 0) ? swave[w - 1] : 0;
  int pre = wpre + (inc - s);         // exclusive prefix for this thread
  #pragma unroll
  for (int i = 0; i < 10; i++) {
    int idx = base + i;
    if (idx < N_NODES) { int o = pre + local[i]; offsets[idx] = o; cursor[idx] = o; }
  }
  if (tid == 1023) offsets[N_NODES] = wpre + inc;
}

// scatter builds order AND the CSR-sorted y2/ss streams directly.
__global__ void k_scatter(const int* __restrict__ recv, const int* __restrict__ send,
                          const float* __restrict__ yr, const float* __restrict__ yi,
                          int* __restrict__ cursor, int* __restrict__ order,
                          float* __restrict__ y2, int* __restrict__ ss) {
  int e = blockIdx.x * 256 + threadIdx.x;
  if (e < N_EDGES) {
    int idx = atomicAdd(&cursor[recv[e]], 1);
    order[idx] = e;
    ss[idx] = send[e];
    float* yy = &y2[(size_t)idx * 20];
    #pragma unroll
    for (int m = 0; m < 9; m++) {
      yy[m] = yr[e * 9 + m];
      yy[9 + m] = yi[e * 9 + m];
    }
    yy[18] = 0.f; yy[19] = 0.f;
  }
}

// ---------------- per-node gather: conv_tp + segment sum -> msg (bf16) ----------
// All streams (tpw, y2, ss) are CSR-position-indexed => fully sequential reads.
// 4-edge load batching; tpw loads non-temporal (read-once 98 MB stream).
__device__ __forceinline__ void edge_fma(const float* __restrict__ y2, int pos,
                                         float xv, float t0, float t1, float t2,
                                         float* mr, float* mi) {
  const float* yy = &y2[(size_t)pos * 20];
  float4 v0 = *(const float4*)&yy[0];    // r0 r1 r2 r3
  float4 v1 = *(const float4*)&yy[4];    // r4 r5 r6 r7
  float4 v2 = *(const float4*)&yy[8];    // r8 i0 i1 i2
  float4 v3 = *(const float4*)&yy[12];   // i3 i4 i5 i6
  float2 v4 = *(const float2*)&yy[16];   // i7 i8
  float xw0 = xv * t0, xw1 = xv * t1, xw2 = xv * t2;
  mr[0] += xw0 * v0.x;
  mr[1] += xw1 * v0.y; mr[2] += xw1 * v0.z; mr[3] += xw1 * v0.w;
  mr[4] += xw2 * v1.x; mr[5] += xw2 * v1.y; mr[6] += xw2 * v1.z;
  mr[7] += xw2 * v1.w; mr[8] += xw2 * v2.x;
  mi[0] += xw0 * v2.y;
  mi[1] += xw1 * v2.z; mi[2] += xw1 * v2.w; mi[3] += xw1 * v3.x;
  mi[4] += xw2 * v3.y; mi[5] += xw2 * v3.z; mi[6] += xw2 * v3.w;
  mi[7] += xw2 * v4.x; mi[8] += xw2 * v4.y;
}

__global__ __launch_bounds__(128, 6) void k_gather(
    const float* __restrict__ h, const unsigned short* __restrict__ tpw,
    const float* __restrict__ y2, const int* __restrict__ ss,
    const int* __restrict__ offsets,
    unsigned short* __restrict__ msg) {
  int u = threadIdx.x;
  int n = blockIdx.x;
  float mr[9] = {}, mi[9] = {};
  int e0 = __builtin_amdgcn_readfirstlane(offsets[n]);
  int e1 = __builtin_amdgcn_readfirstlane(offsets[n + 1]);
  int jj = e0;
  for (; jj + 3 < e1; jj += 4) {
    float xv[4], t0[4], t1[4], t2[4];
    #pragma unroll
    for (int q = 0; q < 4; q++) {
      int pos = jj + q;
      int s = ss[pos];
      const unsigned short* tp = &tpw[(size_t)pos * 384 + u];
      t0[q] = bf2f(__builtin_nontemporal_load(tp));
      t1[q] = bf2f(__builtin_nontemporal_load(tp + 128));
      t2[q] = bf2f(__builtin_nontemporal_load(tp + 256));
      xv[q] = h[s * 128 + u];
    }
    #pragma unroll
    for (int q = 0; q < 4; q++)
      edge_fma(y2, jj + q, xv[q], t0[q], t1[q], t2[q], mr, mi);
  }
  for (; jj < e1; jj++) {
    int s = ss[jj];
    const unsigned short* tp = &tpw[(size_t)jj * 384 + u];
    float t0 = bf2f(__builtin_nontemporal_load(tp));
    float t1 = bf2f(__builtin_nontemporal_load(tp + 128));
    float t2 = bf2f(__builtin_nontemporal_load(tp + 256));
    float xv = h[s * 128 + u];
    edge_fma(y2, jj, xv, t0, t1, t2, mr, mi);
  }
  int g = n >> 3, i = n & 7;
  unsigned short* mg = msg + (size_t)g * 144 * 128;
  mg[(i * 2 + 0) * 128 + u] = f2bf(mr[0]);
  mg[(i * 2 + 1) * 128 + u] = f2bf(mi[0]);
  #pragma unroll
  for (int m = 1; m < 4; m++) {
    mg[(16 + i * 6 + (m - 1)) * 128 + u] = f2bf(mr[m]);
    mg[(16 + i * 6 + 3 + (m - 1)) * 128 + u] = f2bf(mi[m]);
  }
  #pragma unroll
  for (int m = 4; m < 9; m++) {
    mg[(64 + i * 10 + (m - 4)) * 128 + u] = f2bf(mr[m]);
    mg[(64 + i * 10 + 5 + (m - 4)) * 128 + u] = f2bf(mi[m]);
  }
}

// ---------------- linear via MFMA ----------------
// MFMA results staged in LDS (stride-9 scatter, row-padded), then one
// fully-coalesced nontemporal float4 write-out.
#define LIN_ROWPAD 1156   // 1152 + 4 floats; 1156*4 B is 16B-aligned
__global__ __launch_bounds__(256) void k_lin(const unsigned short* __restrict__ msg,
                                             const unsigned short* __restrict__ wlT,
                                             float* __restrict__ out) {
  __shared__ float so[2 * 8 * LIN_ROWPAD];   // 73,984 B
  int tid = threadIdx.x;
  int w = tid >> 6, lane = tid & 63;
  int l15 = lane & 15, quad = lane >> 4;
  int g = blockIdx.x;

  bf16x8 bfr[3][2][4];
  #pragma unroll
  for (int l = 0; l < 3; l++)
    #pragma unroll
    for (int kt = 0; kt < 2; kt++)
      #pragma unroll
      for (int ks = 0; ks < 4; ks++) {
        int ncol = w * 32 + kt * 16 + l15;
        bfr[l][kt][ks] = *(const bf16x8*)&wlT[(l * 128 + ncol) * 128 + ks * 32 + quad * 8];
      }

  const unsigned short* mg = msg + (size_t)g * 144 * 128;

  #pragma unroll
  for (int tile = 0; tile < 9; tile++) {
    const int l = (tile == 0) ? 0 : (tile < 4) ? 1 : 2;
    const int rbase = tile * 16;
    bf16x8 af[4];
    #pragma unroll
    for (int ks = 0; ks < 4; ks++)
      af[ks] = *(const bf16x8*)&mg[(rbase + l15) * 128 + ks * 32 + quad * 8];
    f32x4 acc0 = {}, acc1 = {};
    #pragma unroll
    for (int ks = 0; ks < 4; ks++) {
      acc0 = __builtin_amdgcn_mfma_f32_16x16x32_bf16(af[ks], bfr[l][0][ks], acc0, 0, 0, 0);
      acc1 = __builtin_amdgcn_mfma_f32_16x16x32_bf16(af[ks], bfr[l][1][ks], acc1, 0, 0, 0);
    }
    #pragma unroll
    for (int reg = 0; reg < 4; reg++) {
      int r = rbase + quad * 4 + reg;
      int c, ni, m;
      if (tile == 0) { ni = (r & 15) >> 1; c = r & 1; m = 0; }
      else if (tile < 4) {
        int q = r - 16; ni = q / 6; int rem = q - ni * 6;
        c = rem >= 3; m = 1 + rem - (c ? 3 : 0);
      } else {
        int q = r - 64; ni = q / 10; int rem = q - ni * 10;
        c = rem >= 5; m = 4 + rem - (c ? 5 : 0);
      }
      int k0 = w * 32 + l15;
      float* ob = &so[(c * 8 + ni) * LIN_ROWPAD + m];
      ob[(k0)      * 9] = acc0[reg];
      ob[(k0 + 16) * 9] = acc1[reg];
    }
  }
  __syncthreads();
  // cooperative coalesced write-out: 2*8*1152 floats = 4608 float4
  #pragma unroll
  for (int v = 0; v < 18; v++) {
    int idx = v * 256 + tid;
    int c = idx / 2304;
    int rem = idx - c * 2304;
    int ni = rem / 288;
    int off4 = rem - ni * 288;
    f32x4 p = *(const f32x4*)&so[(c * 8 + ni) * LIN_ROWPAD + off4 * 4];
    f32x4* dst = (f32x4*)&out[(size_t)c * 11520000 + ((size_t)g * 8 + ni) * 1152 +
                              (size_t)off4 * 4];
    __builtin_nontemporal_store(p, dst);
  }
}

// ---------------- launch ----------------
extern "C" void kernel_launch(void* const* d_in, const int* in_sizes, int n_in,
                              void* d_out, int out_size, void* d_ws, size_t ws_size,
                              hipStream_t stream) {
  const float* node_attrs = (const float*)d_in[0];
  const float* node_feats = (const float*)d_in[1];
  const float* ear   = (const float*)d_in[2];
  const float* eai   = (const float*)d_in[3];
  const float* ef    = (const float*)d_in[4];
  const int*   eidx  = (const int*)d_in[5];
  const float* Wup   = (const float*)d_in[6];
  const float* Wskip = (const float*)d_in[7];
  const float* W1    = (const float*)d_in[8];
  const float* W2    = (const float*)d_in[9];
  const float* W3    = (const float*)d_in[10];
  const float* W4    = (const float*)d_in[11];
  const float* Wl0   = (const float*)d_in[12];
  const float* Wl1   = (const float*)d_in[13];
  const float* Wl2   = (const float*)d_in[14];
  float* out = (float*)d_out;

  // workspace layout (bytes):
  char* ws = (char*)d_ws;
  float*          h       = (float*)ws;                              //   5,120,000
  unsigned short* tpw     = (unsigned short*)(ws + 5120000);         //  98,304,000
  unsigned short* msg     = (unsigned short*)(ws + 103424000);       //  46,080,000
  unsigned short* wlT     = (unsigned short*)(ws + 149504000);       //      98,304
  unsigned short* wbT     = (unsigned short*)(ws + 149602304);       //     327,680
  int*            counts  = (int*)(ws + 149929984);
  int*            offsets = (int*)(ws + 149969984);
  int*            cursor  = (int*)(ws + 150010112);
  int*            order   = (int*)(ws + 150050112);                  //     512,000
  unsigned short* w1f     = (unsigned short*)(ws + 150562816);       //       4,096
  unsigned short* w2f     = (unsigned short*)(ws + 150566912);       //       8,192
  unsigned short* w3f     = (unsigned short*)(ws + 150575104);       //       8,192
  unsigned short* w4f     = (unsigned short*)(ws + 150583296);       //      49,152

  // y2 / send_sorted overlaid on the out_r region of d_out (fully consumed
  // by k_gather; k_lin overwrites every element of out_r/out_i afterward).
  float* y2 = (float*)d_out;                                         //  10,240,000
  int*   ss = (int*)((char*)d_out + 10240000);                       //     512,000

  const int* send = eidx;
  const int* recv = eidx + N_EDGES;

  hipMemsetAsync(counts, 0, N_NODES * sizeof(int), stream);
  k_hist<<<dim3(500), dim3(256), 0, stream>>>(recv, counts);
  k_scan<<<dim3(1), dim3(1024), 0, stream>>>(counts, offsets, cursor);
  k_scatter<<<dim3(500), dim3(256), 0, stream>>>(recv, send, ear, eai, cursor,
                                                 order, y2, ss);
  k_wcvt<<<dim3(968), dim3(256), 0, stream>>>(Wskip, Wl0, Wl1, Wl2,
                                              W1, W2, W3, W4,
                                              wbT, wlT, w1f, w2f, w3f, w4f);
  k_h<<<dim3(250), dim3(256), 0, stream>>>(node_feats, Wup, h);
  k_sc<<<dim3(313), dim3(256), 0, stream>>>(node_feats, node_attrs, wbT,
                                            out + 2 * 11520000);
  k_mlp<<<dim3(1000), dim3(256), 0, stream>>>(ef, order, w1f, w2f, w3f, w4f, tpw);
  k_gather<<<dim3(10000), dim3(128), 0, stream>>>(h, tpw, y2, ss, offsets, msg);
  k_lin<<<dim3(1250), dim3(256), 0, stream>>>(msg, wlT, out);
  (void)in_sizes; (void)n_in; (void)out_size; (void)ws_size;
}